// Round 7
// baseline (271.447 us; speedup 1.0000x reference)
//
#include <hip/hip_runtime.h>
#include <hip/hip_bf16.h>

// TreeLSTM on MI355X — round 19: fused leaf+d7 bulk kernel, slim 2-block forest.
// R18 post-mortem: (a) forest slowed 90->116 us because B fragments lost
// register residency (inline L2 reloads per tile in a 2-wave lockstep kernel);
// (b) leafwx+pack added ~50 us of bulk time. Fix both:
//  - leafd7 (2048 blocks, 256 thr): block = (layer,tree,d7-tile). Computes 32
//    leaves (3-gate) into 17 KB LDS, one __syncthreads, then its 16 d7 nodes
//    (children h/c from LDS), writes d7 h/c bf16 to global. Leaf h/c never
//    touch HBM. 75% of node-work at full occupancy.
//  - forest: d6..d0 only. LDS = 127 heap rows = 69 KB -> 2 blocks/CU ->
//    4 waves/SIMD (2x latency hiding). 7 barrier intervals; d6 reads d7 h/c
//    from global (4 independent tiles).
//  - pack_b: weights + x->bf16 for heap rows 0..126 only.

#define TS 511
#define NT 128

typedef __attribute__((ext_vector_type(8))) short short8;
typedef __attribute__((ext_vector_type(4))) float floatx4;

#define MFMA_B16 __builtin_amdgcn_mfma_f32_16x16x32_bf16

// LDS-only barrier: LDS writes visible, global loads NOT drained.
#define BARLDS() do { \
    asm volatile("s_waitcnt lgkmcnt(0)" ::: "memory"); \
    __builtin_amdgcn_s_barrier(); \
    asm volatile("" ::: "memory"); \
} while (0)

__device__ __forceinline__ unsigned short f2b(float f) {
    return __builtin_bit_cast(unsigned short, __float2bfloat16(f));
}
__device__ __forceinline__ float b2f_u(unsigned short u) {
    unsigned v = (unsigned)u << 16;
    return __builtin_bit_cast(float, v);
}
__device__ __forceinline__ float rcp_(float x) { return __builtin_amdgcn_rcpf(x); }
__device__ __forceinline__ float sig_(float x) { return rcp_(1.0f + __expf(-x)); }
__device__ __forceinline__ float tanh_(float x) {
    float a = fabsf(x);
    float t = __expf(-2.0f * a);
    return copysignf((1.0f - t) * rcp_(1.0f + t), x);
}

// ---------------- weight packing + internal-x (rows 0..126) conversion ----------------
// BgU/BgX[(l*512+col)*128+kp] col-major: cols 0..383 = Uiou/Wiou (i|o|u),
//   384..511 = Uf/Wf. bp5[(l*5+g)*128+o]. xb[(tree*127+row)*128+k], row=heap 0..126.
__global__ void pack_b(const float* __restrict__ Wiou, const float* __restrict__ biou,
                       const float* __restrict__ Uiou, const float* __restrict__ Wf,
                       const float* __restrict__ bfv, const float* __restrict__ Uf,
                       const float* __restrict__ feat,
                       unsigned short* __restrict__ BgU, unsigned short* __restrict__ BgX,
                       float* __restrict__ bp5, unsigned short* __restrict__ xb) {
    int tid = blockIdx.x * 256 + threadIdx.x;   // 0..522239
    if (tid < 1280) {
        int l = tid / 640, r = tid % 640, g = r >> 7, o = r & 127;
        bp5[tid] = (g < 3) ? biou[l * 384 + r] : bfv[l * 128 + o];
    }
    if (tid < 131072) {
        int l = tid >> 16, r = tid & 65535, col = r >> 7, kp = r & 127;
        float v = (col < 384) ? Uiou[(l * 384 + col) * 128 + kp]
                              : Uf[(l * 128 + (col - 384)) * 128 + kp];
        BgU[((size_t)(l * 512 + col)) * 128 + kp] = f2b(v);
    } else if (tid < 262144) {
        int e2 = tid - 131072;
        int l = e2 >> 16, r = e2 & 65535, col = r >> 7, kp = r & 127;
        float v = (col < 384) ? Wiou[(l * 384 + col) * 128 + kp]
                              : Wf[(l * 128 + (col - 384)) * 128 + kp];
        BgX[((size_t)(l * 512 + col)) * 128 + kp] = f2b(v);
    } else {
        int e = tid - 262144;                  // 0..260095: rows 0..126 per tree
        int tree = e / 2032;                   // 127 rows * 16 chunks
        int rem = e - tree * 2032;
        int row = rem >> 4, c8 = (rem & 15) * 8;
        const float* src = feat + ((size_t)tree * TS + row) * 128 + c8;
        float4 v0 = *(const float4*)src;
        float4 v1 = *(const float4*)(src + 4);
        short8 r;
        r[0] = (short)f2b(v0.x); r[1] = (short)f2b(v0.y);
        r[2] = (short)f2b(v0.z); r[3] = (short)f2b(v0.w);
        r[4] = (short)f2b(v1.x); r[5] = (short)f2b(v1.y);
        r[6] = (short)f2b(v1.z); r[7] = (short)f2b(v1.w);
        *(short8*)(xb + ((size_t)tree * 127 + row) * 128 + c8) = r;
    }
}

// ---------------- fused leaf + d7 bulk kernel ----------------
// block = l*1024 + tree*8 + t. 256 thr = 4 waves, wave wn owns feats
// [wn*32, wn*32+32). Phase 1: 32 leaves (heap 255+32t..+31) -> LDS h/c.
// Phase 2: 16 d7 nodes (heap 127+16t..+15), children from LDS, h/c -> global
// hb7/cb7[((l*128+tree)*128 + di)*128 + o], di = heap-127.
__global__ __launch_bounds__(256) void leafd7(
        const float* __restrict__ feat, const unsigned short* __restrict__ BgU,
        const unsigned short* __restrict__ BgX, const float* __restrict__ bp5,
        unsigned short* __restrict__ hb7, unsigned short* __restrict__ cb7) {
    const int tid = threadIdx.x;
    const int lane = tid & 63, wn = tid >> 6;
    const int B = blockIdx.x;
    const int l = B >> 10, r = B & 1023, tree = r >> 3, t = r & 7;
    const int quad = lane >> 4, l15 = lane & 15;
    __shared__ __align__(16) unsigned short Lh[32 * 136];
    __shared__ __align__(16) unsigned short Lc[32 * 136];
    const float* xt = feat + (size_t)tree * TS * 128;
    const unsigned short* BU = BgU + (size_t)l * 512 * 128;
    const unsigned short* BX = BgX + (size_t)l * 512 * 128;

    auto cvt8 = [&](const float* p) -> short8 {
        float4 u0 = *(const float4*)p;
        float4 u1 = *(const float4*)(p + 4);
        short8 a;
        a[0] = (short)f2b(u0.x); a[1] = (short)f2b(u0.y);
        a[2] = (short)f2b(u0.z); a[3] = (short)f2b(u0.w);
        a[4] = (short)f2b(u1.x); a[5] = (short)f2b(u1.y);
        a[6] = (short)f2b(u1.z); a[7] = (short)f2b(u1.w);
        return a;
    };

    // ---- phase 1: 32 leaves, gates i/o/u only ----
    {
        floatx4 acc[2][6];
#pragma unroll
        for (int mi = 0; mi < 2; mi++)
#pragma unroll
            for (int ni = 0; ni < 6; ni++)
                acc[mi][ni] = (floatx4){0.f, 0.f, 0.f, 0.f};
#pragma unroll
        for (int kb = 0; kb < 4; kb++) {
            short8 bfr[6];
#pragma unroll
            for (int ni = 0; ni < 6; ni++) {
                int col = (ni >> 1) * 128 + wn * 32 + (ni & 1) * 16 + l15;
                bfr[ni] = *(const short8*)(BX + (size_t)col * 128 + kb * 32 + quad * 8);
            }
#pragma unroll
            for (int mi = 0; mi < 2; mi++) {
                short8 a = cvt8(xt + ((size_t)(255 + 32 * t + mi * 16 + l15)) * 128
                                + kb * 32 + quad * 8);
#pragma unroll
                for (int ni = 0; ni < 6; ni++)
                    acc[mi][ni] = MFMA_B16(a, bfr[ni], acc[mi][ni], 0, 0, 0);
            }
        }
#pragma unroll
        for (int mi = 0; mi < 2; mi++)
#pragma unroll
            for (int ch = 0; ch < 2; ch++) {
                int o = wn * 32 + ch * 16 + l15;
                float bi = bp5[l * 640 + o];
                float bo = bp5[l * 640 + 128 + o];
                float bu = bp5[l * 640 + 256 + o];
#pragma unroll
                for (int rr = 0; rr < 4; rr++) {
                    int idx = mi * 16 + quad * 4 + rr;
                    float iv = sig_(acc[mi][ch][rr] + bi);
                    float ov = sig_(acc[mi][2 + ch][rr] + bo);
                    float uv = tanh_(acc[mi][4 + ch][rr] + bu);
                    float cn = iv * uv;
                    float hn = ov * tanh_(cn);
                    Lh[idx * 136 + o] = f2b(hn);
                    Lc[idx * 136 + o] = f2b(cn);
                }
            }
    }
    __syncthreads();

    // ---- phase 2: 16 d7 nodes, children from LDS ----
    {
        floatx4 ai[2], ao[2], au[2], aw[2], g0[2], g1[2];
#pragma unroll
        for (int ch = 0; ch < 2; ch++) {
            ai[ch] = (floatx4){0.f, 0.f, 0.f, 0.f};
            ao[ch] = ai[ch]; au[ch] = ai[ch]; aw[ch] = ai[ch];
            g0[ch] = ai[ch]; g1[ch] = ai[ch];
        }
#pragma unroll
        for (int kb = 0; kb < 4; kb++) {
            short8 h0 = *(const short8*)&Lh[(2 * l15) * 136 + kb * 32 + quad * 8];
            short8 h1 = *(const short8*)&Lh[(2 * l15 + 1) * 136 + kb * 32 + quad * 8];
            short8 ax = cvt8(xt + ((size_t)(127 + 16 * t + l15)) * 128 + kb * 32 + quad * 8);
#pragma unroll
            for (int ch = 0; ch < 2; ch++) {
                const int cb = wn * 32 + ch * 16 + l15;
                short8 bUi = *(const short8*)(BU + (size_t)(0 * 128 + cb) * 128 + kb * 32 + quad * 8);
                short8 bUo = *(const short8*)(BU + (size_t)(1 * 128 + cb) * 128 + kb * 32 + quad * 8);
                short8 bUu = *(const short8*)(BU + (size_t)(2 * 128 + cb) * 128 + kb * 32 + quad * 8);
                short8 bUf = *(const short8*)(BU + (size_t)(3 * 128 + cb) * 128 + kb * 32 + quad * 8);
                short8 bXi = *(const short8*)(BX + (size_t)(0 * 128 + cb) * 128 + kb * 32 + quad * 8);
                short8 bXo = *(const short8*)(BX + (size_t)(1 * 128 + cb) * 128 + kb * 32 + quad * 8);
                short8 bXu = *(const short8*)(BX + (size_t)(2 * 128 + cb) * 128 + kb * 32 + quad * 8);
                short8 bXf = *(const short8*)(BX + (size_t)(3 * 128 + cb) * 128 + kb * 32 + quad * 8);
                ai[ch] = MFMA_B16(h0, bUi, ai[ch], 0, 0, 0);
                ai[ch] = MFMA_B16(h1, bUi, ai[ch], 0, 0, 0);
                ao[ch] = MFMA_B16(h0, bUo, ao[ch], 0, 0, 0);
                ao[ch] = MFMA_B16(h1, bUo, ao[ch], 0, 0, 0);
                au[ch] = MFMA_B16(h0, bUu, au[ch], 0, 0, 0);
                au[ch] = MFMA_B16(h1, bUu, au[ch], 0, 0, 0);
                g0[ch] = MFMA_B16(h0, bUf, g0[ch], 0, 0, 0);
                g1[ch] = MFMA_B16(h1, bUf, g1[ch], 0, 0, 0);
                ai[ch] = MFMA_B16(ax, bXi, ai[ch], 0, 0, 0);
                ao[ch] = MFMA_B16(ax, bXo, ao[ch], 0, 0, 0);
                au[ch] = MFMA_B16(ax, bXu, au[ch], 0, 0, 0);
                aw[ch] = MFMA_B16(ax, bXf, aw[ch], 0, 0, 0);
            }
        }
#pragma unroll
        for (int ch = 0; ch < 2; ch++) {
            int o = wn * 32 + ch * 16 + l15;
            float bi = bp5[l * 640 + o];
            float bo = bp5[l * 640 + 128 + o];
            float bu = bp5[l * 640 + 256 + o];
            float bf0 = bp5[l * 640 + 384 + o];
            float bf1 = bp5[l * 640 + 512 + o];
#pragma unroll
            for (int rr = 0; rr < 4; rr++) {
                int idx = quad * 4 + rr;
                float iv = sig_(ai[ch][rr] + bi);
                float ov = sig_(ao[ch][rr] + bo);
                float uv = tanh_(au[ch][rr] + bu);
                float f0 = sig_(aw[ch][rr] + g0[ch][rr] + bf0);
                float f1 = sig_(aw[ch][rr] + g1[ch][rr] + bf1);
                float c0 = b2f_u(Lc[(2 * idx) * 136 + o]);
                float c1 = b2f_u(Lc[(2 * idx + 1) * 136 + o]);
                float cn = iv * uv + f0 * c0 + f1 * c1;
                float hn = ov * tanh_(cn);
                size_t gi = (((size_t)(l * 128 + tree)) * 128 + t * 16 + idx) * 128 + o;
                hb7[gi] = f2b(hn);
                cb7[gi] = f2b(cn);
            }
        }
    }
}

// ---------------- forest: d6..d0 only, 69 KB LDS, 2 blocks/CU ----------------
// LDS: heap rows 0..126: h @ S[row*136], c @ S[HC0 + row*136].
__global__ __launch_bounds__(512) void forest(
        const unsigned short* __restrict__ xb16, const unsigned short* __restrict__ hb7,
        const unsigned short* __restrict__ cb7, const unsigned short* __restrict__ BgU,
        const unsigned short* __restrict__ BgX, const float* __restrict__ bp5,
        float* __restrict__ out) {
    __shared__ __align__(16) unsigned short S[34544];
    const int HC0 = 17272;

    const int tid = threadIdx.x;
    const int l = blockIdx.x >> 7, tree = blockIdx.x & 127;
    const int lane = tid & 63, w = tid >> 6;
    const int quad = lane >> 4, l15 = lane & 15;
    const int o = w * 16 + l15;
    const unsigned short* xb = xb16 + (size_t)tree * 127 * 128;
    const unsigned short* lh = hb7 + ((size_t)(l * 128 + tree)) * 128 * 128;
    const unsigned short* lc = cb7 + ((size_t)(l * 128 + tree)) * 128 * 128;
    const unsigned short* BU = BgU + (size_t)l * 512 * 128;
    const unsigned short* BX = BgX + (size_t)l * 512 * 128;

    float bb[5];
#pragma unroll
    for (int g = 0; g < 5; g++) bb[g] = bp5[l * 640 + g * 128 + o];

    auto bu_ = [&](int g, int k) -> short8 {
        return *(const short8*)(BU + ((size_t)(g * 128 + o)) * 128 + k * 32 + quad * 8);
    };
    auto bx_ = [&](int g, int k) -> short8 {
        return *(const short8*)(BX + ((size_t)(g * 128 + o)) * 128 + k * 32 + quad * 8);
    };
    auto ldx = [&](int heap, int k) -> short8 {
        return *(const short8*)(xb + (size_t)heap * 128 + k * 32 + quad * 8);
    };

    // d6 tile j: nodes heap 63+16j+idx; children from global d7 buffers (di)
    auto itile_g6 = [&](int j) {
        const int nA = 63 + 16 * j + l15;
        const int di0 = 32 * j + 2 * l15;
        short8 ax[4];
#pragma unroll
        for (int k = 0; k < 4; k++) ax[k] = ldx(nA, k);
        floatx4 ai = (floatx4){0.f, 0.f, 0.f, 0.f};
        floatx4 ao = ai, au = ai, awx = ai, af0 = ai, af1 = ai;
#pragma unroll
        for (int k = 0; k < 4; k++) {
            short8 h0 = *(const short8*)(lh + (size_t)di0 * 128 + k * 32 + quad * 8);
            short8 h1 = *(const short8*)(lh + (size_t)(di0 + 1) * 128 + k * 32 + quad * 8);
            ai = MFMA_B16(h0, bu_(0, k), ai, 0, 0, 0);
            ai = MFMA_B16(h1, bu_(0, k), ai, 0, 0, 0);
            ao = MFMA_B16(h0, bu_(1, k), ao, 0, 0, 0);
            ao = MFMA_B16(h1, bu_(1, k), ao, 0, 0, 0);
            au = MFMA_B16(h0, bu_(2, k), au, 0, 0, 0);
            au = MFMA_B16(h1, bu_(2, k), au, 0, 0, 0);
            af0 = MFMA_B16(h0, bu_(3, k), af0, 0, 0, 0);
            af1 = MFMA_B16(h1, bu_(3, k), af1, 0, 0, 0);
            ai = MFMA_B16(ax[k], bx_(0, k), ai, 0, 0, 0);
            ao = MFMA_B16(ax[k], bx_(1, k), ao, 0, 0, 0);
            au = MFMA_B16(ax[k], bx_(2, k), au, 0, 0, 0);
            awx = MFMA_B16(ax[k], bx_(3, k), awx, 0, 0, 0);
        }
#pragma unroll
        for (int rr = 0; rr < 4; rr++) {
            int idx = quad * 4 + rr;
            int node = 63 + 16 * j + idx;
            int dic = 32 * j + 2 * idx;
            float iv = sig_(ai[rr] + bb[0]);
            float ov = sig_(ao[rr] + bb[1]);
            float uv = tanh_(au[rr] + bb[2]);
            float f0 = sig_(awx[rr] + af0[rr] + bb[3]);
            float f1 = sig_(awx[rr] + af1[rr] + bb[4]);
            float c0 = b2f_u(lc[(size_t)dic * 128 + o]);
            float c1 = b2f_u(lc[(size_t)(dic + 1) * 128 + o]);
            float cn = iv * uv + f0 * c0 + f1 * c1;
            float hn = ov * tanh_(cn);
            S[node * 136 + o] = f2b(hn);
            S[HC0 + node * 136 + o] = f2b(cn);
        }
    };

    // internal tile with LDS children: nodes heap base+idx (idx<nv)
    auto itile_l = [&](int base, int nv, bool isRoot) {
        const int rl = (l15 < nv) ? l15 : nv - 1;
        const int nA = base + rl;
        const int ch0 = 2 * nA + 1;
        short8 ax[4];
#pragma unroll
        for (int k = 0; k < 4; k++) ax[k] = ldx(nA, k);
        floatx4 ai = (floatx4){0.f, 0.f, 0.f, 0.f};
        floatx4 ao = ai, au = ai, awx = ai, af0 = ai, af1 = ai;
#pragma unroll
        for (int k = 0; k < 4; k++) {
            short8 h0 = *(const short8*)&S[ch0 * 136 + k * 32 + quad * 8];
            short8 h1 = *(const short8*)&S[(ch0 + 1) * 136 + k * 32 + quad * 8];
            ai = MFMA_B16(h0, bu_(0, k), ai, 0, 0, 0);
            ai = MFMA_B16(h1, bu_(0, k), ai, 0, 0, 0);
            ao = MFMA_B16(h0, bu_(1, k), ao, 0, 0, 0);
            ao = MFMA_B16(h1, bu_(1, k), ao, 0, 0, 0);
            au = MFMA_B16(h0, bu_(2, k), au, 0, 0, 0);
            au = MFMA_B16(h1, bu_(2, k), au, 0, 0, 0);
            af0 = MFMA_B16(h0, bu_(3, k), af0, 0, 0, 0);
            af1 = MFMA_B16(h1, bu_(3, k), af1, 0, 0, 0);
            ai = MFMA_B16(ax[k], bx_(0, k), ai, 0, 0, 0);
            ao = MFMA_B16(ax[k], bx_(1, k), ao, 0, 0, 0);
            au = MFMA_B16(ax[k], bx_(2, k), au, 0, 0, 0);
            awx = MFMA_B16(ax[k], bx_(3, k), awx, 0, 0, 0);
        }
#pragma unroll
        for (int rr = 0; rr < 4; rr++) {
            int idx = quad * 4 + rr;
            if (idx < nv) {
                int node = base + idx;
                int ch = 2 * node + 1;
                float iv = sig_(ai[rr] + bb[0]);
                float ov = sig_(ao[rr] + bb[1]);
                float uv = tanh_(au[rr] + bb[2]);
                float f0 = sig_(awx[rr] + af0[rr] + bb[3]);
                float f1 = sig_(awx[rr] + af1[rr] + bb[4]);
                float c0 = b2f_u(S[HC0 + ch * 136 + o]);
                float c1 = b2f_u(S[HC0 + (ch + 1) * 136 + o]);
                float cn = iv * uv + f0 * c0 + f1 * c1;
                float hn = ov * tanh_(cn);
                S[node * 136 + o] = f2b(hn);
                S[HC0 + node * 136 + o] = f2b(cn);
                if (isRoot) {
                    out[((size_t)l * 128 + tree) * 128 + o] = hn;
                    out[32768 + ((size_t)l * 128 + tree) * 128 + o] = cn;
                }
            }
        }
    };

    // ---- interval 1: d6 (4 independent tiles, children from global) ----
#pragma unroll 2
    for (int j = 0; j < 4; j++) itile_g6(j);
    BARLDS();
    // ---- interval 2: d5 (2 tiles) ----
    itile_l(31, 16, false);
    itile_l(47, 16, false);
    BARLDS();
    // ---- intervals 3..7: d4..d0 ----
    itile_l(15, 16, false);
    BARLDS();
    itile_l(7, 8, false);
    BARLDS();
    itile_l(3, 4, false);
    BARLDS();
    itile_l(1, 2, false);
    BARLDS();
    itile_l(0, 1, true);
}

extern "C" void kernel_launch(void* const* d_in, const int* in_sizes, int n_in,
                              void* d_out, int out_size, void* d_ws, size_t ws_size,
                              hipStream_t stream) {
    const float* feat = (const float*)d_in[0];
    const float* Wiou = (const float*)d_in[1];
    const float* biou = (const float*)d_in[2];
    const float* Uiou = (const float*)d_in[3];
    const float* Wf   = (const float*)d_in[4];
    const float* bfv  = (const float*)d_in[5];
    const float* Uf   = (const float*)d_in[6];
    float* out = (float*)d_out;

    // ws (bf16 shorts): BgU[131072] BgX[131072] xb[2080768] hb7[4194304]
    //   cb7[4194304] + bp5(f32)[1280]  ~= 21.5 MB
    unsigned short* BgU = (unsigned short*)d_ws;
    unsigned short* BgX = BgU + (size_t)131072;
    unsigned short* xb16 = BgX + (size_t)131072;
    unsigned short* hb7 = xb16 + (size_t)2080768;
    unsigned short* cb7 = hb7 + (size_t)4194304;
    float* bp5 = (float*)(cb7 + (size_t)4194304);

    pack_b<<<2040, 256, 0, stream>>>(Wiou, biou, Uiou, Wf, bfv, Uf, feat,
                                     BgU, BgX, bp5, xb16);
    leafd7<<<2048, 256, 0, stream>>>(feat, BgU, BgX, bp5, hb7, cb7);
    forest<<<256, 512, 0, stream>>>(xb16, hb7, cb7, BgU, BgX, bp5, out);
}

// Round 8
// 206.006 us; speedup vs baseline: 1.3177x; 1.3177x over previous
//
#include <hip/hip_runtime.h>
#include <hip/hip_bf16.h>

// TreeLSTM on MI355X — round 20: R14 fused forest at 2 blocks/CU.
// R19 post-mortem: bulk leafd7 was latency-crippled (96 VGPR, 64 dependent
// L2 B-loads/tile, MfmaUtil 6%). R14's fused forest remains the best kernel
// (427 TF effective). Its defect: 139 KB LDS -> 1 block/CU -> 2 waves/SIMD
// lockstep (55% stall). Fix: d7 h/c -> GLOBAL (16.8 MB, read back once by
// d6), LDS shrinks to 69 KB (flat heap rows 0..126; leaf dbuf overlays the
// d6 region during the leaf/d7 phase) -> 2 blocks/CU -> 4 waves/SIMD, two
// independent tree-chains per CU hide each other's barrier stalls.
// Everything else is R14's verified structure. 2 dispatches.

#define TS 511
#define NT 128
#define NN (NT * TS)   // 65408

typedef __attribute__((ext_vector_type(8))) short short8;
typedef __attribute__((ext_vector_type(4))) float floatx4;

#define MFMA_B16 __builtin_amdgcn_mfma_f32_16x16x32_bf16

// LDS-only barrier: LDS writes visible, global loads NOT drained.
#define BARLDS() do { \
    asm volatile("s_waitcnt lgkmcnt(0)" ::: "memory"); \
    __builtin_amdgcn_s_barrier(); \
    asm volatile("" ::: "memory"); \
} while (0)

__device__ __forceinline__ unsigned short f2b(float f) {
    return __builtin_bit_cast(unsigned short, __float2bfloat16(f));
}
__device__ __forceinline__ float b2f_u(unsigned short u) {
    unsigned v = (unsigned)u << 16;
    return __builtin_bit_cast(float, v);
}
__device__ __forceinline__ float rcp_(float x) { return __builtin_amdgcn_rcpf(x); }
__device__ __forceinline__ float sig_(float x) { return rcp_(1.0f + __expf(-x)); }
__device__ __forceinline__ float tanh_(float x) {
    float a = fabsf(x);
    float t = __expf(-2.0f * a);
    return copysignf((1.0f - t) * rcp_(1.0f + t), x);
}

// ---------------- weight packing + x conversion (R14 verbatim) ----------------
// BgU/BgX[(l*512+col)*128+kp] col-major: cols 0..383 = Uiou/Wiou (i|o|u),
//   384..511 = Uf/Wf. bp5[(l*5+g)*128+o]. xb[node*128+k]: all-node bf16 x.
__global__ void pack_b(const float* __restrict__ Wiou, const float* __restrict__ biou,
                       const float* __restrict__ Uiou, const float* __restrict__ Wf,
                       const float* __restrict__ bfv, const float* __restrict__ Uf,
                       const float* __restrict__ feat,
                       unsigned short* __restrict__ BgU, unsigned short* __restrict__ BgX,
                       float* __restrict__ bp5, unsigned short* __restrict__ xb) {
    int tid = blockIdx.x * 256 + threadIdx.x;   // 0..1308671
    if (tid < 1280) {
        int l = tid / 640, r = tid % 640, g = r >> 7, o = r & 127;
        bp5[tid] = (g < 3) ? biou[l * 384 + r] : bfv[l * 128 + o];
    }
    if (tid < 131072) {
        int l = tid >> 16, r = tid & 65535, col = r >> 7, kp = r & 127;
        float v = (col < 384) ? Uiou[(l * 384 + col) * 128 + kp]
                              : Uf[(l * 128 + (col - 384)) * 128 + kp];
        BgU[((size_t)(l * 512 + col)) * 128 + kp] = f2b(v);
    } else if (tid < 262144) {
        int e2 = tid - 131072;
        int l = e2 >> 16, r = e2 & 65535, col = r >> 7, kp = r & 127;
        float v = (col < 384) ? Wiou[(l * 384 + col) * 128 + kp]
                              : Wf[(l * 128 + (col - 384)) * 128 + kp];
        BgX[((size_t)(l * 512 + col)) * 128 + kp] = f2b(v);
    } else {
        int e = tid - 262144;                  // < 1046528, 8 elems each
        size_t base = (size_t)e * 8;
        float4 v0 = *(const float4*)(feat + base);
        float4 v1 = *(const float4*)(feat + base + 4);
        short8 r;
        r[0] = (short)f2b(v0.x); r[1] = (short)f2b(v0.y);
        r[2] = (short)f2b(v0.z); r[3] = (short)f2b(v0.w);
        r[4] = (short)f2b(v1.x); r[5] = (short)f2b(v1.y);
        r[6] = (short)f2b(v1.z); r[7] = (short)f2b(v1.w);
        *(short8*)(xb + base) = r;
    }
}

// ---------------- fused forest, 69 KB LDS, 2 blocks/CU ----------------
// LDS (halfwords, row stride 136): flat heap rows 0..126 (d6..d0):
//   h @ S[row*136], c @ S[HC0 + row*136].
// Leaf double-buffer overlays rows 63..126 during the leaf/d7 phase:
//   buf b rows 63+b*32 .. 63+b*32+31 (same rows in h- and c-space).
// d7 h/c -> global hb7/cb7[((l*128+tree)*128 + (heap-127))*128 + o].
__global__ __launch_bounds__(512) void forest(
        const unsigned short* __restrict__ xb16, const unsigned short* __restrict__ BgU,
        const unsigned short* __restrict__ BgX, const float* __restrict__ bp5,
        unsigned short* __restrict__ hb7, unsigned short* __restrict__ cb7,
        float* __restrict__ out) {
    __shared__ __align__(16) unsigned short S[34544];
    const int HC0 = 17272;

    const int tid = threadIdx.x;
    const int l = blockIdx.x >> 7, tree = blockIdx.x & 127;
    const int lane = tid & 63, w = tid >> 6;
    const int quad = lane >> 4, l15 = lane & 15;
    const int o = w * 16 + l15;
    const unsigned short* xb = xb16 + (size_t)tree * TS * 128;
    unsigned short* lh = hb7 + ((size_t)(l * 128 + tree)) * 128 * 128;
    unsigned short* lc = cb7 + ((size_t)(l * 128 + tree)) * 128 * 128;
    const unsigned short* BU = BgU + (size_t)l * 512 * 128;
    const unsigned short* BX = BgX + (size_t)l * 512 * 128;

    // resident B fragments: gates i,o,u,f (f0/f1 share Wf and Uf cols)
    short8 bU[4][4], bX[4][4];
#pragma unroll
    for (int g = 0; g < 4; g++) {
        const size_t cb = (size_t)(g * 128 + o) * 128;
#pragma unroll
        for (int kbl = 0; kbl < 4; kbl++) {
            bU[g][kbl] = *(const short8*)(BU + cb + kbl * 32 + quad * 8);
            bX[g][kbl] = *(const short8*)(BX + cb + kbl * 32 + quad * 8);
        }
    }
    float bb[5];
#pragma unroll
    for (int g = 0; g < 5; g++) bb[g] = bp5[l * 640 + g * 128 + o];

    auto ldx = [&](int heap, int kbl) -> short8 {
        return *(const short8*)(xb + (size_t)heap * 128 + kbl * 32 + quad * 8);
    };

    // 16-row leaf tile: x-only gates -> leaf buffer rows (h- and c-space)
    auto ltile = [&](int heapA, int selfR) {
        floatx4 ai = (floatx4){0.f, 0.f, 0.f, 0.f};
        floatx4 ao = ai, au = ai;
#pragma unroll
        for (int kbl = 0; kbl < 4; kbl++) {
            short8 ax = ldx(heapA, kbl);
            ai = MFMA_B16(ax, bX[0][kbl], ai, 0, 0, 0);
            ao = MFMA_B16(ax, bX[1][kbl], ao, 0, 0, 0);
            au = MFMA_B16(ax, bX[2][kbl], au, 0, 0, 0);
        }
#pragma unroll
        for (int r = 0; r < 4; r++) {
            int idx = quad * 4 + r;
            float iv = sig_(ai[r] + bb[0]);
            float ov = sig_(ao[r] + bb[1]);
            float uv = tanh_(au[r] + bb[2]);
            float cn = iv * uv;
            float hn = ov * tanh_(cn);
            S[(selfR + idx) * 136 + o] = f2b(hn);
            S[HC0 + (selfR + idx) * 136 + o] = f2b(cn);
        }
    };

    // d7 tile t: nodes heap 127+16t+idx; children from leaf buffer b (LDS);
    // h/c written to GLOBAL.
    auto d7g = [&](int t, int b) {
        const int chAh = 63 + b * 32 + 2 * l15;
        floatx4 ai = (floatx4){0.f, 0.f, 0.f, 0.f};
        floatx4 ao = ai, au = ai, awx = ai, af0 = ai, af1 = ai;
#pragma unroll
        for (int kbl = 0; kbl < 4; kbl++) {
            short8 h0 = *(const short8*)&S[chAh * 136 + kbl * 32 + quad * 8];
            short8 h1 = *(const short8*)&S[(chAh + 1) * 136 + kbl * 32 + quad * 8];
            short8 ax = ldx(127 + 16 * t + l15, kbl);
            ai = MFMA_B16(h0, bU[0][kbl], ai, 0, 0, 0);
            ai = MFMA_B16(h1, bU[0][kbl], ai, 0, 0, 0);
            ao = MFMA_B16(h0, bU[1][kbl], ao, 0, 0, 0);
            ao = MFMA_B16(h1, bU[1][kbl], ao, 0, 0, 0);
            au = MFMA_B16(h0, bU[2][kbl], au, 0, 0, 0);
            au = MFMA_B16(h1, bU[2][kbl], au, 0, 0, 0);
            af0 = MFMA_B16(h0, bU[3][kbl], af0, 0, 0, 0);
            af1 = MFMA_B16(h1, bU[3][kbl], af1, 0, 0, 0);
            ai = MFMA_B16(ax, bX[0][kbl], ai, 0, 0, 0);
            ao = MFMA_B16(ax, bX[1][kbl], ao, 0, 0, 0);
            au = MFMA_B16(ax, bX[2][kbl], au, 0, 0, 0);
            awx = MFMA_B16(ax, bX[3][kbl], awx, 0, 0, 0);
        }
#pragma unroll
        for (int r = 0; r < 4; r++) {
            int idx = quad * 4 + r;
            float iv = sig_(ai[r] + bb[0]);
            float ov = sig_(ao[r] + bb[1]);
            float uv = tanh_(au[r] + bb[2]);
            float f0 = sig_(awx[r] + af0[r] + bb[3]);
            float f1 = sig_(awx[r] + af1[r] + bb[4]);
            float c0 = b2f_u(S[HC0 + (63 + b * 32 + 2 * idx) * 136 + o]);
            float c1 = b2f_u(S[HC0 + (63 + b * 32 + 2 * idx + 1) * 136 + o]);
            float cn = iv * uv + f0 * c0 + f1 * c1;
            float hn = ov * tanh_(cn);
            size_t gi = (size_t)(t * 16 + idx) * 128 + o;
            lh[gi] = f2b(hn);
            lc[gi] = f2b(cn);
        }
    };

    // d6 tile j: nodes heap 63+16j+idx; children (d7) from GLOBAL; h/c -> LDS.
    auto d6g = [&](int j) {
        const int di0 = 32 * j + 2 * l15;
        floatx4 ai = (floatx4){0.f, 0.f, 0.f, 0.f};
        floatx4 ao = ai, au = ai, awx = ai, af0 = ai, af1 = ai;
#pragma unroll
        for (int kbl = 0; kbl < 4; kbl++) {
            short8 h0 = *(const short8*)(lh + (size_t)di0 * 128 + kbl * 32 + quad * 8);
            short8 h1 = *(const short8*)(lh + (size_t)(di0 + 1) * 128 + kbl * 32 + quad * 8);
            short8 ax = ldx(63 + 16 * j + l15, kbl);
            ai = MFMA_B16(h0, bU[0][kbl], ai, 0, 0, 0);
            ai = MFMA_B16(h1, bU[0][kbl], ai, 0, 0, 0);
            ao = MFMA_B16(h0, bU[1][kbl], ao, 0, 0, 0);
            ao = MFMA_B16(h1, bU[1][kbl], ao, 0, 0, 0);
            au = MFMA_B16(h0, bU[2][kbl], au, 0, 0, 0);
            au = MFMA_B16(h1, bU[2][kbl], au, 0, 0, 0);
            af0 = MFMA_B16(h0, bU[3][kbl], af0, 0, 0, 0);
            af1 = MFMA_B16(h1, bU[3][kbl], af1, 0, 0, 0);
            ai = MFMA_B16(ax, bX[0][kbl], ai, 0, 0, 0);
            ao = MFMA_B16(ax, bX[1][kbl], ao, 0, 0, 0);
            au = MFMA_B16(ax, bX[2][kbl], au, 0, 0, 0);
            awx = MFMA_B16(ax, bX[3][kbl], awx, 0, 0, 0);
        }
#pragma unroll
        for (int r = 0; r < 4; r++) {
            int idx = quad * 4 + r;
            int node = 63 + 16 * j + idx;
            int dic = 32 * j + 2 * idx;
            float iv = sig_(ai[r] + bb[0]);
            float ov = sig_(ao[r] + bb[1]);
            float uv = tanh_(au[r] + bb[2]);
            float f0 = sig_(awx[r] + af0[r] + bb[3]);
            float f1 = sig_(awx[r] + af1[r] + bb[4]);
            float c0 = b2f_u(lc[(size_t)dic * 128 + o]);
            float c1 = b2f_u(lc[(size_t)(dic + 1) * 128 + o]);
            float cn = iv * uv + f0 * c0 + f1 * c1;
            float hn = ov * tanh_(cn);
            S[node * 136 + o] = f2b(hn);
            S[HC0 + node * 136 + o] = f2b(cn);
        }
    };

    // internal tile with LDS children (flat heap): nodes heap base+idx (idx<nv)
    auto itile_l = [&](int base, int nv, bool isRoot) {
        const int rl = (l15 < nv) ? l15 : nv - 1;
        const int nA = base + rl;
        const int ch0 = 2 * nA + 1;
        floatx4 ai = (floatx4){0.f, 0.f, 0.f, 0.f};
        floatx4 ao = ai, au = ai, awx = ai, af0 = ai, af1 = ai;
#pragma unroll
        for (int kbl = 0; kbl < 4; kbl++) {
            short8 h0 = *(const short8*)&S[ch0 * 136 + kbl * 32 + quad * 8];
            short8 h1 = *(const short8*)&S[(ch0 + 1) * 136 + kbl * 32 + quad * 8];
            short8 ax = ldx(nA, kbl);
            ai = MFMA_B16(h0, bU[0][kbl], ai, 0, 0, 0);
            ai = MFMA_B16(h1, bU[0][kbl], ai, 0, 0, 0);
            ao = MFMA_B16(h0, bU[1][kbl], ao, 0, 0, 0);
            ao = MFMA_B16(h1, bU[1][kbl], ao, 0, 0, 0);
            au = MFMA_B16(h0, bU[2][kbl], au, 0, 0, 0);
            au = MFMA_B16(h1, bU[2][kbl], au, 0, 0, 0);
            af0 = MFMA_B16(h0, bU[3][kbl], af0, 0, 0, 0);
            af1 = MFMA_B16(h1, bU[3][kbl], af1, 0, 0, 0);
            ai = MFMA_B16(ax, bX[0][kbl], ai, 0, 0, 0);
            ao = MFMA_B16(ax, bX[1][kbl], ao, 0, 0, 0);
            au = MFMA_B16(ax, bX[2][kbl], au, 0, 0, 0);
            awx = MFMA_B16(ax, bX[3][kbl], awx, 0, 0, 0);
        }
#pragma unroll
        for (int r = 0; r < 4; r++) {
            int idx = quad * 4 + r;
            if (idx < nv) {
                int node = base + idx;
                int ch = 2 * node + 1;
                float iv = sig_(ai[r] + bb[0]);
                float ov = sig_(ao[r] + bb[1]);
                float uv = tanh_(au[r] + bb[2]);
                float f0 = sig_(awx[r] + af0[r] + bb[3]);
                float f1 = sig_(awx[r] + af1[r] + bb[4]);
                float c0 = b2f_u(S[HC0 + ch * 136 + o]);
                float c1 = b2f_u(S[HC0 + (ch + 1) * 136 + o]);
                float cn = iv * uv + f0 * c0 + f1 * c1;
                float hn = ov * tanh_(cn);
                S[node * 136 + o] = f2b(hn);
                S[HC0 + node * 136 + o] = f2b(cn);
                if (isRoot) {
                    out[((size_t)l * 128 + tree) * 128 + o] = hn;
                    out[32768 + ((size_t)l * 128 + tree) * 128 + o] = cn;
                }
            }
        }
    };

    // ---- prologue: leaf pair 0 -> buf 0 (rows 63..94) ----
    ltile(255 + l15, 63);
    ltile(271 + l15, 63 + 16);
    BARLDS();

    // ---- leaf/d7 loop: 8 intervals, d7 h/c -> global ----
#pragma unroll 1
    for (int t = 0; t < 8; t++) {
        const int b = t & 1;
        if (t < 7) {
            const int b2 = b ^ 1;
            ltile(287 + 32 * t + l15, 63 + b2 * 32);
            ltile(303 + 32 * t + l15, 63 + b2 * 32 + 16);
        }
        d7g(t, b);
        BARLDS();
    }

    // publish d7 global writes block-wide, then d6 reads them
    __threadfence();
    __syncthreads();

    // ---- d6: 4 independent tiles (global children) -> LDS rows 63..126 ----
#pragma unroll 2
    for (int j = 0; j < 4; j++) d6g(j);
    BARLDS();
    // ---- d5 (2 tiles) ----
    itile_l(31, 16, false);
    itile_l(47, 16, false);
    BARLDS();
    // ---- d4..d0 ----
    itile_l(15, 16, false);
    BARLDS();
    itile_l(7, 8, false);
    BARLDS();
    itile_l(3, 4, false);
    BARLDS();
    itile_l(1, 2, false);
    BARLDS();
    itile_l(0, 1, true);
}

extern "C" void kernel_launch(void* const* d_in, const int* in_sizes, int n_in,
                              void* d_out, int out_size, void* d_ws, size_t ws_size,
                              hipStream_t stream) {
    const float* feat = (const float*)d_in[0];
    const float* Wiou = (const float*)d_in[1];
    const float* biou = (const float*)d_in[2];
    const float* Uiou = (const float*)d_in[3];
    const float* Wf   = (const float*)d_in[4];
    const float* bfv  = (const float*)d_in[5];
    const float* Uf   = (const float*)d_in[6];
    float* out = (float*)d_out;

    // ws (bf16 shorts): BgU[131072] BgX[131072] xb16[NN*128=8372224]
    //   hb7[4194304] cb7[4194304] + bp5(f32)[1280]  ~= 34 MB
    unsigned short* BgU = (unsigned short*)d_ws;
    unsigned short* BgX = BgU + (size_t)131072;
    unsigned short* xb16 = BgX + (size_t)131072;
    unsigned short* hb7 = xb16 + (size_t)NN * 128;
    unsigned short* cb7 = hb7 + (size_t)4194304;
    float* bp5 = (float*)(cb7 + (size_t)4194304);

    pack_b<<<5112, 256, 0, stream>>>(Wiou, biou, Uiou, Wf, bfv, Uf, feat,
                                     BgU, BgX, bp5, xb16);
    forest<<<256, 512, 0, stream>>>(xb16, BgU, BgX, bp5, hb7, cb7, out);
}